// Round 1
// baseline (1483.944 us; speedup 1.0000x reference)
//
#include <hip/hip_runtime.h>
#include <cstdint>
#include <cstddef>

#define HDIM 2048
#define VOCAB 32000
#define BT 4096      // B*T tokens
#define NVB 250      // VOCAB / 128
#define BETA_F 0.1f

typedef __bf16 bf16x8 __attribute__((ext_vector_type(8)));
typedef float f32x4 __attribute__((ext_vector_type(4)));
typedef unsigned short ushort8v __attribute__((ext_vector_type(8)));

// ---------------------------------------------------------------- helpers
__device__ __forceinline__ unsigned short f2bf(float f) {
  unsigned int u = __float_as_uint(f);
  u += 0x7fffu + ((u >> 16) & 1u);   // round-to-nearest-even
  return (unsigned short)(u >> 16);
}

__device__ __forceinline__ void async_lds16(const void* g, void* l) {
  __builtin_amdgcn_global_load_lds(
      (__attribute__((address_space(1))) void*)g,
      (__attribute__((address_space(3))) void*)l,
      16, 0, 0);
}

// ---------------------------------------------------------------- cast fp32 -> bf16 (8 elems/thread)
__global__ void cast_bf16_kernel(const float* __restrict__ src,
                                 unsigned short* __restrict__ dst, int n8) {
  int i = blockIdx.x * blockDim.x + threadIdx.x;
  int stride = gridDim.x * blockDim.x;
  for (; i < n8; i += stride) {
    const float4* s4 = (const float4*)src + (size_t)i * 2;
    float4 a = s4[0];
    float4 b = s4[1];
    ushort8v o;
    o[0] = f2bf(a.x); o[1] = f2bf(a.y); o[2] = f2bf(a.z); o[3] = f2bf(a.w);
    o[4] = f2bf(b.x); o[5] = f2bf(b.y); o[6] = f2bf(b.z); o[7] = f2bf(b.w);
    *((ushort8v*)dst + i) = o;
  }
}

// ---------------------------------------------------------------- GEMM + per-chunk (max, sumexp) partials
// A: [BT][HDIM] bf16, Wq: [VOCAB][HDIM] bf16, part: [BT][NVB] float2(max, sumexp)
__global__ __launch_bounds__(256) void gemm_lse(
    const unsigned short* __restrict__ A,
    const unsigned short* __restrict__ Wq,
    float2* __restrict__ part) {
  __shared__ __align__(16) unsigned short ldsA[128 * 32];
  __shared__ __align__(16) unsigned short ldsB[128 * 32];
  __shared__ float lmx[2][128];
  __shared__ float lsm[2][128];

  const int rb = blockIdx.x;   // 0..31   (token rows / 128)
  const int vb = blockIdx.y;   // 0..249  (vocab cols / 128)
  const int tid = threadIdx.x;
  const int lane = tid & 63;
  const int w = tid >> 6;

  // staging: thread tid covers bf16 elems [tid*8, tid*8+8) of the 128x32 tile
  const int srow = tid >> 2;           // 0..63 (first half), +64 second half
  const int scol = (tid & 3) << 3;     // 0,8,16,24
  const unsigned short* gA = A  + (size_t)(rb * 128 + srow) * HDIM + scol;
  const unsigned short* gB = Wq + (size_t)(vb * 128 + srow) * HDIM + scol;
  const size_t halfStep = (size_t)64 * HDIM;

  char* lA = (char*)ldsA + w * 1024;   // wave-uniform LDS base (+ lane*16 by HW)
  char* lB = (char*)ldsB + w * 1024;

  f32x4 acc[4][4] = {};

  const int rbase = ((w >> 1) * 64) + (lane & 15);
  const int cbase = ((w & 1) * 64) + (lane & 15);
  const int koff = (lane >> 4) * 8;

  for (int k0 = 0; k0 < HDIM; k0 += 32) {
    __syncthreads();
    async_lds16(gA + k0, lA);
    async_lds16(gA + halfStep + k0, lA + 4096);
    async_lds16(gB + k0, lB);
    async_lds16(gB + halfStep + k0, lB + 4096);
    __syncthreads();

    bf16x8 af[4], bfr[4];
#pragma unroll
    for (int mi = 0; mi < 4; ++mi)
      af[mi] = *(const bf16x8*)&ldsA[(rbase + mi * 16) * 32 + koff];
#pragma unroll
    for (int ni = 0; ni < 4; ++ni)
      bfr[ni] = *(const bf16x8*)&ldsB[(cbase + ni * 16) * 32 + koff];
#pragma unroll
    for (int mi = 0; mi < 4; ++mi)
#pragma unroll
      for (int ni = 0; ni < 4; ++ni)
        acc[mi][ni] = __builtin_amdgcn_mfma_f32_16x16x32_bf16(
            af[mi], bfr[ni], acc[mi][ni], 0, 0, 0);
  }

  // epilogue: per-row (max, sumexp) over this block's 128 vocab cols
  // C/D layout (verified): col = lane&15, row = (lane>>4)*4 + reg
  const int colHalf = w & 1;
#pragma unroll
  for (int mi = 0; mi < 4; ++mi) {
#pragma unroll
    for (int r = 0; r < 4; ++r) {
      float m = acc[mi][0][r];
      m = fmaxf(m, acc[mi][1][r]);
      m = fmaxf(m, acc[mi][2][r]);
      m = fmaxf(m, acc[mi][3][r]);
#pragma unroll
      for (int o = 1; o < 16; o <<= 1)
        m = fmaxf(m, __shfl_xor(m, o, 64));
      float s = 0.f;
#pragma unroll
      for (int ni = 0; ni < 4; ++ni)
        s += __expf(acc[mi][ni][r] - m);
#pragma unroll
      for (int o = 1; o < 16; o <<= 1)
        s += __shfl_xor(s, o, 64);
      if ((lane & 15) == 0) {
        int rl = (w >> 1) * 64 + mi * 16 + (lane >> 4) * 4 + r;
        lmx[colHalf][rl] = m;
        lsm[colHalf][rl] = s;
      }
    }
  }
  __syncthreads();
  if (tid < 128) {
    float m0 = lmx[0][tid], m1 = lmx[1][tid];
    float s0 = lsm[0][tid], s1 = lsm[1][tid];
    float M = fmaxf(m0, m1);
    float S = s0 * __expf(m0 - M) + s1 * __expf(m1 - M);
    part[(size_t)(rb * 128 + tid) * NVB + vb] = make_float2(M, S);
  }
}

// ---------------------------------------------------------------- exact fp32 target logit: dot(x, W[y])
__global__ void target_logit(const float* __restrict__ x, const float* __restrict__ xr,
                             const float* __restrict__ W, const float* __restrict__ Wr,
                             const int* __restrict__ y, float* __restrict__ tlog) {
  int wid = (blockIdx.x * blockDim.x + threadIdx.x) >> 6;  // 0..8191
  int lane = threadIdx.x & 63;
  int which = wid >> 12;
  int tok = wid & 4095;
  int yy = y[tok];
  int ys = (yy == -100) ? 0 : yy;
  const float* xv = (which ? xr : x) + (size_t)tok * HDIM;
  const float* wv = (which ? Wr : W) + (size_t)ys * HDIM;
  const float4* x4 = (const float4*)xv;
  const float4* w4 = (const float4*)wv;
  float sum = 0.f;
  for (int i = lane; i < HDIM / 4; i += 64) {
    float4 a = x4[i], b = w4[i];
    sum += a.x * b.x + a.y * b.y + a.z * b.z + a.w * b.w;
  }
#pragma unroll
  for (int o = 1; o < 64; o <<= 1) sum += __shfl_xor(sum, o, 64);
  if (lane == 0) tlog[wid] = sum;
}

// ---------------------------------------------------------------- merge partials -> per-token logp
__global__ void lse_combine(const float2* __restrict__ part,
                            const float* __restrict__ tlog,
                            float* __restrict__ ptok) {
  int wid = (blockIdx.x * blockDim.x + threadIdx.x) >> 6;  // 0..8191
  int lane = threadIdx.x & 63;
  const float2* p = part + (size_t)wid * NVB;
  float m = -INFINITY, s = 0.f;
  for (int i = lane; i < NVB; i += 64) {
    float2 v = p[i];
    float M = fmaxf(m, v.x);
    s = s * __expf(m - M) + v.y * __expf(v.x - M);
    m = M;
  }
#pragma unroll
  for (int o = 1; o < 64; o <<= 1) {
    float mo = __shfl_xor(m, o, 64);
    float so = __shfl_xor(s, o, 64);
    float M = fmaxf(m, mo);
    s = s * __expf(m - M) + so * __expf(mo - M);
    m = M;
  }
  if (lane == 0) ptok[wid] = tlog[wid] - (m + logf(s));
}

// ---------------------------------------------------------------- masked per-seq mean + DPO loss
__global__ void final_loss(const float* __restrict__ ptok,
                           const int* __restrict__ y, float* __restrict__ out) {
  __shared__ float rs[256];
  __shared__ float rc[256];
  __shared__ float seq[8];
  int tid = threadIdx.x;
  for (int s = 0; s < 8; ++s) {
    int which = s >> 2, b = s & 3;
    float lsum = 0.f, lcnt = 0.f;
    for (int t = tid; t < 1024; t += 256) {
      int yy = y[b * 1024 + t];
      if (yy != -100) {
        lsum += ptok[which * 4096 + b * 1024 + t];
        lcnt += 1.f;
      }
    }
    rs[tid] = lsum; rc[tid] = lcnt;
    __syncthreads();
    for (int o = 128; o > 0; o >>= 1) {
      if (tid < o) { rs[tid] += rs[tid + o]; rc[tid] += rc[tid + o]; }
      __syncthreads();
    }
    if (tid == 0) seq[s] = rs[0] / rc[0];
    __syncthreads();
  }
  if (tid == 0) {
    // seq[0..3] = policy logps b=0..3 ; seq[4..7] = ref logps
    float d0 = BETA_F * ((seq[0] - seq[4]) - (seq[2] - seq[6]));
    float d1 = BETA_F * ((seq[1] - seq[5]) - (seq[3] - seq[7]));
    // -log_sigmoid(z) = softplus(-z)
    auto sp = [](float a) { return fmaxf(a, 0.f) + log1pf(expf(-fabsf(a))); };
    out[0] = (sp(-d0) + sp(-d1)) * 0.5f;
  }
}

// ---------------------------------------------------------------- launch
extern "C" void kernel_launch(void* const* d_in, const int* in_sizes, int n_in,
                              void* d_out, int out_size, void* d_ws, size_t ws_size,
                              hipStream_t stream) {
  const float* x   = (const float*)d_in[0];
  const float* xr  = (const float*)d_in[1];
  const int*   y   = (const int*)d_in[2];
  const float* Wf  = (const float*)d_in[3];
  const float* Wrf = (const float*)d_in[4];
  float* out = (float*)d_out;

  char* ws = (char*)d_ws;
  size_t off = 0;
  auto alloc = [&](size_t bytes) -> void* {
    void* p = ws + off;
    off = (off + bytes + 255) & ~(size_t)255;
    return p;
  };
  unsigned short* Xb  = (unsigned short*)alloc((size_t)BT * HDIM * 2);
  unsigned short* Xrb = (unsigned short*)alloc((size_t)BT * HDIM * 2);
  unsigned short* Wb  = (unsigned short*)alloc((size_t)VOCAB * HDIM * 2);  // reused for W and W_ref
  float2* part = (float2*)alloc((size_t)2 * BT * NVB * sizeof(float2));
  float*  tlog = (float*)alloc((size_t)2 * BT * sizeof(float));
  float*  ptok = (float*)alloc((size_t)2 * BT * sizeof(float));

  cast_bf16_kernel<<<1024, 256, 0, stream>>>(x,  Xb,  BT * HDIM / 8);
  cast_bf16_kernel<<<1024, 256, 0, stream>>>(xr, Xrb, BT * HDIM / 8);
  cast_bf16_kernel<<<2048, 256, 0, stream>>>(Wf, Wb, VOCAB * HDIM / 8);

  dim3 gg(32, NVB);
  gemm_lse<<<gg, 256, 0, stream>>>(Xb, Wb, part);

  cast_bf16_kernel<<<2048, 256, 0, stream>>>(Wrf, Wb, VOCAB * HDIM / 8);
  gemm_lse<<<gg, 256, 0, stream>>>(Xrb, Wb, part + (size_t)BT * NVB);

  target_logit<<<2048, 256, 0, stream>>>(x, xr, Wf, Wrf, y, tlog);
  lse_combine<<<2048, 256, 0, stream>>>(part, tlog, ptok);
  final_loss<<<1, 256, 0, stream>>>(ptok, y, out);
}

// Round 2
// 1223.011 us; speedup vs baseline: 1.2134x; 1.2134x over previous
//
#include <hip/hip_runtime.h>
#include <cstdint>
#include <cstddef>

#define HDIM 2048
#define VOCAB 32000
#define BT 4096      // B*T tokens
#define NVB 125      // VOCAB / 256
#define BETA_F 0.1f

typedef __bf16 bf16x8 __attribute__((ext_vector_type(8)));
typedef float f32x4 __attribute__((ext_vector_type(4)));
typedef unsigned short ushort8v __attribute__((ext_vector_type(8)));

// ---------------------------------------------------------------- helpers
__device__ __forceinline__ unsigned short f2bf(float f) {
  unsigned int u = __float_as_uint(f);
  u += 0x7fffu + ((u >> 16) & 1u);   // round-to-nearest-even
  return (unsigned short)(u >> 16);
}

__device__ __forceinline__ void async_lds16(const void* g, void* l) {
  __builtin_amdgcn_global_load_lds(
      (__attribute__((address_space(1))) void*)g,
      (__attribute__((address_space(3))) void*)l,
      16, 0, 0);
}

#define BAR() __builtin_amdgcn_s_barrier()
#define LGKM0() do { asm volatile("s_waitcnt lgkmcnt(0)" ::: "memory"); \
                     __builtin_amdgcn_sched_barrier(0); } while (0)
#define VMCNT(n) do { asm volatile("s_waitcnt vmcnt(" #n ")" ::: "memory"); \
                      __builtin_amdgcn_sched_barrier(0); } while (0)

// ---------------------------------------------------------------- cast fp32 -> bf16 (8 elems/thread)
__global__ void cast_bf16_kernel(const float* __restrict__ src,
                                 unsigned short* __restrict__ dst, int n8) {
  int i = blockIdx.x * blockDim.x + threadIdx.x;
  int stride = gridDim.x * blockDim.x;
  for (; i < n8; i += stride) {
    const float4* s4 = (const float4*)src + (size_t)i * 2;
    float4 a = s4[0];
    float4 b = s4[1];
    ushort8v o;
    o[0] = f2bf(a.x); o[1] = f2bf(a.y); o[2] = f2bf(a.z); o[3] = f2bf(a.w);
    o[4] = f2bf(b.x); o[5] = f2bf(b.y); o[6] = f2bf(b.z); o[7] = f2bf(b.w);
    *((ushort8v*)dst + i) = o;
  }
}

// ---------------------------------------------------------------- 256x256 8-phase GEMM + LSE partials
// A: [BT][HDIM] bf16, Wq: [VOCAB][HDIM] bf16, part: [BT][NVB] float2(max, sumexp)
//
// LDS: [buf][A=0/B=1][half][16 KiB]. Half-tile layout: [kk(2)][row(128)][col(32)] bf16,
// st_16x32 swizzle: physical = logical ^ (((logical>>9)&1)<<5)  (bit9 == bit3 of row).
// global_load_lds writes linearly -> source address pre-swizzled (lane' = lane ^ ((lane&32)>>4)).
__global__ __launch_bounds__(512, 2) void gemm_lse256(
    const unsigned short* __restrict__ A,
    const unsigned short* __restrict__ Wq,
    float2* __restrict__ part) {
  __shared__ __align__(16) char lds[2][2][2][16384];

  const int tid = threadIdx.x;
  const int lane = tid & 63;
  const int w = tid >> 6;        // wave 0..7
  const int wm = w >> 2;         // 0..1 : M-half owner
  const int wn = w & 3;          // 0..3 : N-quarter owner
  const int mb = blockIdx.x;     // 0..15
  const int nb = blockIdx.y;     // 0..124

  // ---- staging addressing (source pre-swizzled to undo the read-side XOR) ----
  const int lanep = lane ^ ((lane & 32) >> 4);
  const int rw = w * 16 + (lanep >> 2);     // row within 128-row half
  const int cw = (lanep & 3) * 8;           // col elems within a 32-col kk block
  const unsigned short* Ag = A  + (size_t)(mb * 256 + rw) * HDIM + cw;
  const unsigned short* Bg = Wq + (size_t)(nb * 256 + rw) * HDIM + cw;

#define STAGE(opsel, buf, h, T) do {                                          \
    const unsigned short* _g = (opsel) ? Bg : Ag;                             \
    char* _l = &lds[buf][opsel][h][0];                                        \
    async_lds16(_g + (size_t)(h) * 128 * HDIM + (T) * 64,      _l + w * 1024);        \
    async_lds16(_g + (size_t)(h) * 128 * HDIM + (T) * 64 + 32, _l + 8192 + w * 1024); \
  } while (0)

  // ---- fragment reads (swizzled) ----
  const int l15 = lane & 15;
  const int kbyte = (lane >> 4) * 16;
#define FRAG(dst, halfptr, row, kk) do {                                      \
    int _r = (row);                                                           \
    int _L = (kk) * 8192 + _r * 64 + kbyte;                                   \
    dst = *(const bf16x8*)((halfptr) + (_L ^ (((_r >> 3) & 1) << 5)));        \
  } while (0)

  const char* A0h = &lds[0][0][wm][0];
  const char* A1h = &lds[1][0][wm][0];
  const char* B0h = &lds[0][1][wn >> 1][0];
  const char* B1h = &lds[1][1][wn >> 1][0];
  const int brow = (wn & 1) * 64;

  f32x4 acc[8][4] = {};
  bf16x8 aF[4][2], bF[4][2];

#define READ_A(base, mi0) do {                                                \
    _Pragma("unroll") for (int mi = 0; mi < 4; ++mi) {                        \
      FRAG(aF[mi][0], base, ((mi0) + mi) * 16 + l15, 0);                      \
      FRAG(aF[mi][1], base, ((mi0) + mi) * 16 + l15, 1);                      \
    } } while (0)
#define READ_B(base) do {                                                     \
    _Pragma("unroll") for (int ni = 0; ni < 4; ++ni) {                        \
      FRAG(bF[ni][0], base, brow + ni * 16 + l15, 0);                         \
      FRAG(bF[ni][1], base, brow + ni * 16 + l15, 1);                         \
    } } while (0)
#define MFMA_Q(MI0, NI0) do {                                                 \
    __builtin_amdgcn_s_setprio(1);                                            \
    _Pragma("unroll") for (int kk = 0; kk < 2; ++kk)                          \
    _Pragma("unroll") for (int mi = 0; mi < 4; ++mi)                          \
    _Pragma("unroll") for (int ni = 0; ni < 2; ++ni)                          \
      acc[(MI0) + mi][(NI0) + ni] = __builtin_amdgcn_mfma_f32_16x16x32_bf16(  \
          aF[mi][kk], bF[(NI0) + ni][kk], acc[(MI0) + mi][(NI0) + ni], 0, 0, 0); \
    __builtin_amdgcn_s_setprio(0);                                            \
  } while (0)

  // ---- prologue: tile0 (all 4 halves) + tile1 (B0,B1,A0); A1(1) staged at iter0 ph1
  STAGE(0, 0, 0, 0); STAGE(0, 0, 1, 0); STAGE(1, 0, 0, 0); STAGE(1, 0, 1, 0);
  STAGE(1, 1, 0, 1); STAGE(1, 1, 1, 1); STAGE(0, 1, 0, 1);
  VMCNT(6);
  BAR();

  // ---- main loop: 16 iterations, 2 K-tiles each (tiles 0..31) ----
  for (int i = 0; i < 16; ++i) {
    const int t1 = 2 * i + 1;
    const int se = (2 * i + 2 > 30) ? 30 : 2 * i + 2;  // even stage tile (buf0)
    const int so = (2 * i + 3 > 31) ? 31 : 2 * i + 3;  // odd  stage tile (buf1)

    // phase 1: q0 of tile t0 (buf0); reads: aF(mi0-3)+bF(all)
    READ_A(A0h, 0);
    READ_B(B0h);
    STAGE(0, 1, 1, t1);          // A-half1 of t1 (A(t1-2) reads ended prev ph7)
    BAR(); LGKM0();
    MFMA_Q(0, 0);
    BAR();

    // phase 2
    STAGE(1, 0, 0, se);          // B-half0(se); B(t0) reads ended ph1
    BAR(); LGKM0();
    MFMA_Q(0, 2);
    BAR();

    // phase 3
    READ_A(A0h, 4);
    STAGE(1, 0, 1, se);          // B-half1(se)
    BAR(); LGKM0();
    MFMA_Q(4, 0);
    BAR();

    // phase 4
    STAGE(0, 0, 0, se);          // A-half0(se); A(t0) reads ended ph3
    VMCNT(6);                    // tile t1 fully landed (3 halves in flight)
    BAR();
    MFMA_Q(4, 2);
    BAR();

    // phase 5: q0 of tile t1 (buf1)
    READ_A(A1h, 0);
    READ_B(B1h);
    STAGE(0, 0, 1, se);          // A-half1(se)
    BAR(); LGKM0();
    MFMA_Q(0, 0);
    BAR();

    // phase 6
    STAGE(1, 1, 0, so);          // B-half0(so); B(t1) reads ended ph5
    BAR(); LGKM0();
    MFMA_Q(0, 2);
    BAR();

    // phase 7
    READ_A(A1h, 4);
    STAGE(1, 1, 1, so);          // B-half1(so)
    BAR(); LGKM0();
    MFMA_Q(4, 0);
    BAR();

    // phase 8
    STAGE(0, 1, 0, so);          // A-half0(so); A(t1) reads ended ph7
    VMCNT(6);                    // tile se fully landed
    BAR();
    MFMA_Q(4, 2);
    BAR();
  }
  VMCNT(0);                      // drain redundant tail re-stages before LDS reuse
  BAR();

  // ---- fused LSE epilogue over this block's 256 vocab cols ----
  // C/D layout: col = lane&15, row = (lane>>4)*4 + reg
  float* red = (float*)&lds[0][0][0][0];   // mx: red[wn*256+row], sm: red[1024+...]
#pragma unroll
  for (int mi = 0; mi < 8; ++mi) {
#pragma unroll
    for (int r = 0; r < 4; ++r) {
      float m = fmaxf(fmaxf(acc[mi][0][r], acc[mi][1][r]),
                      fmaxf(acc[mi][2][r], acc[mi][3][r]));
#pragma unroll
      for (int o = 1; o < 16; o <<= 1) m = fmaxf(m, __shfl_xor(m, o, 64));
      float s = __expf(acc[mi][0][r] - m) + __expf(acc[mi][1][r] - m) +
                __expf(acc[mi][2][r] - m) + __expf(acc[mi][3][r] - m);
#pragma unroll
      for (int o = 1; o < 16; o <<= 1) s += __shfl_xor(s, o, 64);
      if (l15 == 0) {
        int row = wm * 128 + mi * 16 + (lane >> 4) * 4 + r;
        red[wn * 256 + row] = m;
        red[1024 + wn * 256 + row] = s;
      }
    }
  }
  __syncthreads();
  if (tid < 256) {
    float m0 = red[tid], m1 = red[256 + tid], m2 = red[512 + tid], m3 = red[768 + tid];
    float M = fmaxf(fmaxf(m0, m1), fmaxf(m2, m3));
    float S = red[1024 + tid] * __expf(m0 - M) + red[1280 + tid] * __expf(m1 - M) +
              red[1536 + tid] * __expf(m2 - M) + red[1792 + tid] * __expf(m3 - M);
    part[(size_t)(mb * 256 + tid) * NVB + nb] = make_float2(M, S);
  }
#undef STAGE
#undef FRAG
#undef READ_A
#undef READ_B
#undef MFMA_Q
}

// ---------------------------------------------------------------- exact fp32 target logit: dot(x, W[y])
__global__ void target_logit(const float* __restrict__ x, const float* __restrict__ xr,
                             const float* __restrict__ W, const float* __restrict__ Wr,
                             const int* __restrict__ y, float* __restrict__ tlog) {
  int wid = (blockIdx.x * blockDim.x + threadIdx.x) >> 6;  // 0..8191
  int lane = threadIdx.x & 63;
  int which = wid >> 12;
  int tok = wid & 4095;
  int yy = y[tok];
  int ys = (yy == -100) ? 0 : yy;
  const float* xv = (which ? xr : x) + (size_t)tok * HDIM;
  const float* wv = (which ? Wr : W) + (size_t)ys * HDIM;
  const float4* x4 = (const float4*)xv;
  const float4* w4 = (const float4*)wv;
  float sum = 0.f;
  for (int i = lane; i < HDIM / 4; i += 64) {
    float4 a = x4[i], b = w4[i];
    sum += a.x * b.x + a.y * b.y + a.z * b.z + a.w * b.w;
  }
#pragma unroll
  for (int o = 1; o < 64; o <<= 1) sum += __shfl_xor(sum, o, 64);
  if (lane == 0) tlog[wid] = sum;
}

// ---------------------------------------------------------------- merge partials -> per-token logp
__global__ void lse_combine(const float2* __restrict__ part,
                            const float* __restrict__ tlog,
                            float* __restrict__ ptok) {
  int wid = (blockIdx.x * blockDim.x + threadIdx.x) >> 6;  // 0..8191
  int lane = threadIdx.x & 63;
  const float2* p = part + (size_t)wid * NVB;
  float m = -INFINITY, s = 0.f;
  for (int i = lane; i < NVB; i += 64) {
    float2 v = p[i];
    float M = fmaxf(m, v.x);
    s = s * __expf(m - M) + v.y * __expf(v.x - M);
    m = M;
  }
#pragma unroll
  for (int o = 1; o < 64; o <<= 1) {
    float mo = __shfl_xor(m, o, 64);
    float so = __shfl_xor(s, o, 64);
    float M = fmaxf(m, mo);
    s = s * __expf(m - M) + so * __expf(mo - M);
    m = M;
  }
  if (lane == 0) ptok[wid] = tlog[wid] - (m + logf(s));
}

// ---------------------------------------------------------------- masked per-seq mean + DPO loss
__global__ void final_loss(const float* __restrict__ ptok,
                           const int* __restrict__ y, float* __restrict__ out) {
  __shared__ float rs[256];
  __shared__ float rc[256];
  __shared__ float seq[8];
  int tid = threadIdx.x;
  for (int s = 0; s < 8; ++s) {
    int which = s >> 2, b = s & 3;
    float lsum = 0.f, lcnt = 0.f;
    for (int t = tid; t < 1024; t += 256) {
      int yy = y[b * 1024 + t];
      if (yy != -100) {
        lsum += ptok[which * 4096 + b * 1024 + t];
        lcnt += 1.f;
      }
    }
    rs[tid] = lsum; rc[tid] = lcnt;
    __syncthreads();
    for (int o = 128; o > 0; o >>= 1) {
      if (tid < o) { rs[tid] += rs[tid + o]; rc[tid] += rc[tid + o]; }
      __syncthreads();
    }
    if (tid == 0) seq[s] = rs[0] / rc[0];
    __syncthreads();
  }
  if (tid == 0) {
    float d0 = BETA_F * ((seq[0] - seq[4]) - (seq[2] - seq[6]));
    float d1 = BETA_F * ((seq[1] - seq[5]) - (seq[3] - seq[7]));
    auto sp = [](float a) { return fmaxf(a, 0.f) + log1pf(expf(-fabsf(a))); };
    out[0] = (sp(-d0) + sp(-d1)) * 0.5f;
  }
}

// ---------------------------------------------------------------- launch
extern "C" void kernel_launch(void* const* d_in, const int* in_sizes, int n_in,
                              void* d_out, int out_size, void* d_ws, size_t ws_size,
                              hipStream_t stream) {
  const float* x   = (const float*)d_in[0];
  const float* xr  = (const float*)d_in[1];
  const int*   y   = (const int*)d_in[2];
  const float* Wf  = (const float*)d_in[3];
  const float* Wrf = (const float*)d_in[4];
  float* out = (float*)d_out;

  char* ws = (char*)d_ws;
  size_t off = 0;
  auto alloc = [&](size_t bytes) -> void* {
    void* p = ws + off;
    off = (off + bytes + 255) & ~(size_t)255;
    return p;
  };
  unsigned short* Xb  = (unsigned short*)alloc((size_t)BT * HDIM * 2);
  unsigned short* Xrb = (unsigned short*)alloc((size_t)BT * HDIM * 2);
  unsigned short* Wb  = (unsigned short*)alloc((size_t)VOCAB * HDIM * 2);  // reused
  float2* part = (float2*)alloc((size_t)2 * BT * NVB * sizeof(float2));
  float*  tlog = (float*)alloc((size_t)2 * BT * sizeof(float));
  float*  ptok = (float*)alloc((size_t)2 * BT * sizeof(float));

  cast_bf16_kernel<<<1024, 256, 0, stream>>>(x,  Xb,  BT * HDIM / 8);
  cast_bf16_kernel<<<1024, 256, 0, stream>>>(xr, Xrb, BT * HDIM / 8);
  cast_bf16_kernel<<<2048, 256, 0, stream>>>(Wf, Wb, VOCAB * HDIM / 8);

  dim3 gg(16, NVB);
  gemm_lse256<<<gg, 512, 0, stream>>>(Xb, Wb, part);

  cast_bf16_kernel<<<2048, 256, 0, stream>>>(Wrf, Wb, VOCAB * HDIM / 8);
  gemm_lse256<<<gg, 512, 0, stream>>>(Xrb, Wb, part + (size_t)BT * NVB);

  target_logit<<<2048, 256, 0, stream>>>(x, xr, Wf, Wrf, y, tlog);
  lse_combine<<<2048, 256, 0, stream>>>(part, tlog, ptok);
  final_loss<<<1, 256, 0, stream>>>(ptok, y, out);
}